// Round 2
// baseline (314.106 us; speedup 1.0000x reference)
//
#include <hip/hip_runtime.h>
#include <stdint.h>

#define D_MODEL 1024
#define SEQ 2048
#define NBATCH 4

typedef __attribute__((ext_vector_type(4))) float f32x4;
typedef __attribute__((ext_vector_type(8))) __bf16 bf16x8;
typedef __attribute__((ext_vector_type(4))) unsigned short u16x4;

__device__ __forceinline__ float b2f(unsigned short u) {
    union { unsigned int i; float f; } c; c.i = ((unsigned int)u) << 16; return c.f;
}
__device__ __forceinline__ unsigned short f2b(float f) {
    union { float f; unsigned int i; } c; c.f = f;
    unsigned int u = c.i;
    u += 0x7FFFu + ((u >> 16) & 1u);
    return (unsigned short)(u >> 16);
}

__device__ __forceinline__ void glds16(void* lds, const void* g) {
    __builtin_amdgcn_global_load_lds((const __attribute__((address_space(1))) void*)g,
                                     (__attribute__((address_space(3))) void*)lds,
                                     16, 0, 0);
}

// XCD-aware tile remap (8 XCDs, bid%8 = xcd). Each XCD owns a contiguous
// y-band of height gy/8 across all x,z so its L2 holds only its A-band + the
// shared B panel. Pure permutation; requires gy % 8 == 0 (grids: gy in {16,64}).
__device__ __forceinline__ void xcd_map(int& xx, int& yy, int& zz)
{
    const int gx = gridDim.x, gy = gridDim.y;
    int bid = blockIdx.x + gx * (blockIdx.y + gy * blockIdx.z);
    const int H = gy >> 3;
    const int xcd = bid & 7;
    int slot = bid >> 3;
    yy = xcd * H + (slot % H);
    slot /= H;
    xx = slot % gx;
    zz = slot / gx;
}

// ---------------------------------------------------------------------------
// GEMM core, 2-phase pipelined (guide §5.5 T3 "minimum 2-phase" recipe,
// m248-verified structure): double-buffered BK=32 tiles; per iteration:
//   STAGE(next tile -> buf^1)   // issue global_load_lds first
//   ds_read(buf) -> MFMA        // compute overlaps the in-flight loads
//   __syncthreads()             // vmcnt(0)+lgkmcnt(0)+s_barrier (compiler-emitted)
// Correctness is by construction (no inline asm, no counted waits):
//  - reads of buf are consumed into registers before the sync (compiler
//    lgkmcnt precedes the consuming MFMAs), so next iteration's writes to buf
//    (issued after the sync) cannot clobber them;
//  - writes to buf^1 are fully landed at the sync (vmcnt(0)) before anyone
//    reads buf^1 next iteration.
// LDS per buffer: [128 rows][32 cols] bf16, 64B rows, 4x16B slots/row.
// XOR swizzle: slot s of row r holds global chunk s ^ ((r>>1)&3), applied on
// the glds *source* address (glds LDS writes are linear: base + lane*16) and
// on the ds_read address -> b128 reads hit the 8-clk floor (0 extra conflicts,
// verified class in round-0 counters).
// ---------------------------------------------------------------------------
__device__ __forceinline__ void gemm_tile(const unsigned short* __restrict__ A,
                                          const unsigned short* __restrict__ Bt,
                                          int K, int m0, int n0,
                                          f32x4 (&acc)[4][4])
{
    __shared__ alignas(16) unsigned short As[2 * 128 * 32];
    __shared__ alignas(16) unsigned short Bs[2 * 128 * 32];

    const int t    = threadIdx.x;                  // 256 threads = 4 waves
    const int wave = t >> 6;
    const int lane = t & 63;

    // staging: wave w, lane i covers rows {w*16 + i/4, 64 + w*16 + i/4},
    // slot i&3 holding source chunk (i&3) ^ ((row>>1)&3). Note row and row+64
    // give the same ((row>>1)&3), so one source offset serves both j's.
    const int srow = (wave << 4) + (lane >> 2);    // 0..63
    const int sch  = ((lane & 3) ^ ((srow >> 1) & 3)) * 8;

    const unsigned short* Ag = A  + (long)(m0 + srow) * K + sch;
    const unsigned short* Bg = Bt + (long)(n0 + srow) * K + sch;

    char* AsW = (char*)As + wave * 1024;           // wave-uniform glds dest
    char* BsW = (char*)Bs + wave * 1024;

    const int fr = lane & 15, quad = lane >> 4;
    const int wm = (wave >> 1) * 64, wn = (wave & 1) * 64;
    const int slot = (quad ^ ((fr >> 1) & 3)) * 16;   // swizzled read slot
    const int aoff = (wm + fr) * 64 + slot;
    const int boff = (wn + fr) * 64 + slot;

    auto stage = [&](int buf, int ko) {
        #pragma unroll
        for (int j = 0; j < 2; ++j) {
            glds16(AsW + buf * 8192 + j * 4096, Ag + (long)(j * 64) * K + ko);
            glds16(BsW + buf * 8192 + j * 4096, Bg + (long)(j * 64) * K + ko);
        }
    };

    stage(0, 0);
    __syncthreads();

    int buf = 0;
    for (int k0 = 0; k0 < K; k0 += 32) {
        if (k0 + 32 < K) stage(buf ^ 1, k0 + 32);   // issue next tile first

        const char* Ab = (const char*)As + buf * 8192;
        const char* Bb = (const char*)Bs + buf * 8192;
        bf16x8 af[4], bv[4];
        #pragma unroll
        for (int i = 0; i < 4; ++i)
            af[i] = *(const bf16x8*)(Ab + aoff + i * 1024);
        #pragma unroll
        for (int i = 0; i < 4; ++i)
            bv[i] = *(const bf16x8*)(Bb + boff + i * 1024);

        #pragma unroll
        for (int mi = 0; mi < 4; ++mi)
            #pragma unroll
            for (int ni = 0; ni < 4; ++ni)
                acc[mi][ni] = __builtin_amdgcn_mfma_f32_16x16x32_bf16(
                                  af[mi], bv[ni], acc[mi][ni], 0, 0, 0);

        __syncthreads();                            // drain + barrier
        buf ^= 1;
    }
}

// Plain-store GEMM, z-batched via element strides. OutT = ushort(bf16) | float.
template<bool BIAS, typename OutT>
__global__ __launch_bounds__(256)
void gemm_bt(const unsigned short* __restrict__ A,
             const unsigned short* __restrict__ Bt,
             const float* __restrict__ bias,
             OutT* __restrict__ C,
             int N, int K, long sA, long sB, long sC)
{
    int xx, yy, zz;
    xcd_map(xx, yy, zz);
    A  += (long)zz * sA;
    Bt += (long)zz * sB;
    C  += (long)zz * sC;
    const int m0 = yy * 128;
    const int n0 = xx * 128;

    f32x4 acc[4][4] = {};
    gemm_tile(A, Bt, K, m0, n0, acc);

    const int t = threadIdx.x, wave = t >> 6, lane = t & 63;
    const int wm = (wave >> 1) * 64, wn = (wave & 1) * 64;
    const int fr = lane & 15, quad = lane >> 4;

    float bb[4] = {0.f, 0.f, 0.f, 0.f};
    if (BIAS) {
        #pragma unroll
        for (int ni = 0; ni < 4; ++ni)
            bb[ni] = bias[n0 + wn + ni * 16 + fr];
    }

    // C/D layout (HW-verified): col = lane&15, row = quad*4 + reg
    #pragma unroll
    for (int mi = 0; mi < 4; ++mi) {
        const int rowb = m0 + wm + mi * 16 + quad * 4;
        #pragma unroll
        for (int ni = 0; ni < 4; ++ni) {
            const int col = n0 + wn + ni * 16 + fr;
            f32x4 v = acc[mi][ni];
            if constexpr (sizeof(OutT) == 4) {
                #pragma unroll
                for (int r = 0; r < 4; ++r)
                    C[(long)(rowb + r) * N + col] = v[r] + bb[ni];
            } else {
                #pragma unroll
                for (int r = 0; r < 4; ++r)
                    C[(long)(rowb + r) * N + col] = (OutT)f2b(v[r] + bb[ni]);
            }
        }
    }
}

// Fused QKV projection: grid (8, 64, 3); remapped z selects weight/bias/output.
// V (z==2) stores transposed per batch: Vt[b][n][s], b = row>>11, s = row&2047.
__global__ __launch_bounds__(256)
void qkv_gemm(const unsigned short* __restrict__ xb,
              const unsigned short* __restrict__ Wqt,
              const unsigned short* __restrict__ Wkt,
              const unsigned short* __restrict__ Wvt,
              const float* __restrict__ bq, const float* __restrict__ bk,
              const float* __restrict__ bv,
              unsigned short* __restrict__ Q, unsigned short* __restrict__ Kb,
              unsigned short* __restrict__ Vt)
{
    int xx, yy, zz;
    xcd_map(xx, yy, zz);

    const unsigned short* Bt; const float* bias; unsigned short* C; bool tstore = false;
    switch (zz) {
        case 0:  Bt = Wqt; bias = bq; C = Q;  break;
        case 1:  Bt = Wkt; bias = bk; C = Kb; break;
        default: Bt = Wvt; bias = bv; C = Vt; tstore = true; break;
    }
    const int m0 = yy * 128;
    const int n0 = xx * 128;
    const int N = D_MODEL, K = D_MODEL;

    f32x4 acc[4][4] = {};
    gemm_tile(xb, Bt, K, m0, n0, acc);

    const int t = threadIdx.x, wave = t >> 6, lane = t & 63;
    const int wm = (wave >> 1) * 64, wn = (wave & 1) * 64;
    const int fr = lane & 15, quad = lane >> 4;

    float bb[4];
    #pragma unroll
    for (int ni = 0; ni < 4; ++ni)
        bb[ni] = bias[n0 + wn + ni * 16 + fr];

    #pragma unroll
    for (int mi = 0; mi < 4; ++mi) {
        const int rowb = m0 + wm + mi * 16 + quad * 4;
        #pragma unroll
        for (int ni = 0; ni < 4; ++ni) {
            const int col = n0 + wn + ni * 16 + fr;
            f32x4 v = acc[mi][ni];
            if (!tstore) {
                #pragma unroll
                for (int r = 0; r < 4; ++r)
                    C[(long)(rowb + r) * N + col] = f2b(v[r] + bb[ni]);
            } else {
                u16x4 pk;
                #pragma unroll
                for (int r = 0; r < 4; ++r)
                    pk[r] = f2b(v[r] + bb[ni]);
                unsigned short* dst = C + ((long)(rowb >> 11)) * ((long)N * SEQ)
                                        + (long)col * SEQ + (rowb & (SEQ - 1));
                *(u16x4*)dst = pk;
            }
        }
    }
}

// In-place softmax over rows of 2048 bf16 raw scores, 1/sqrt(1024) folded in.
__global__ __launch_bounds__(256)
void softmax_inplace(unsigned short* __restrict__ S)
{
    const long row = blockIdx.x;
    unsigned short* s = S + row * SEQ;
    const int t = threadIdx.x;

    u16x4 a = ((const u16x4*)s)[t];
    u16x4 b = ((const u16x4*)s)[t + 256];
    float v[8];
    #pragma unroll
    for (int i = 0; i < 4; ++i) { v[i] = b2f(a[i]); v[4 + i] = b2f(b[i]); }

    float mx = v[0];
    #pragma unroll
    for (int i = 1; i < 8; ++i) mx = fmaxf(mx, v[i]);
    #pragma unroll
    for (int off = 32; off; off >>= 1) mx = fmaxf(mx, __shfl_xor(mx, off));

    __shared__ float red[8];
    const int wv = t >> 6, ln = t & 63;
    if (ln == 0) red[wv] = mx;
    __syncthreads();
    mx = fmaxf(fmaxf(red[0], red[1]), fmaxf(red[2], red[3]));

    const float sc = 0.03125f;
    float e[8], sum = 0.f;
    #pragma unroll
    for (int i = 0; i < 8; ++i) { e[i] = __expf((v[i] - mx) * sc); sum += e[i]; }
    #pragma unroll
    for (int off = 32; off; off >>= 1) sum += __shfl_xor(sum, off);
    if (ln == 0) red[4 + wv] = sum;
    __syncthreads();
    sum = (red[4] + red[5]) + (red[6] + red[7]);
    const float inv = 1.f / sum;

    u16x4 o;
    #pragma unroll
    for (int i = 0; i < 4; ++i) o[i] = f2b(e[i] * inv);
    ((u16x4*)s)[t] = o;
    #pragma unroll
    for (int i = 0; i < 4; ++i) o[i] = f2b(e[4 + i] * inv);
    ((u16x4*)s)[t + 256] = o;
}

// Fused prep: blocks [0,8192) cast x fp32->bf16 (1024 elems each);
// blocks [8192,12288) transpose+cast the four weights (32x32 tiles).
__global__ __launch_bounds__(256)
void prep(const float* __restrict__ x, unsigned short* __restrict__ xb,
          const float* __restrict__ W0, const float* __restrict__ W1,
          const float* __restrict__ W2, const float* __restrict__ W3,
          unsigned short* __restrict__ T0, unsigned short* __restrict__ T1,
          unsigned short* __restrict__ T2, unsigned short* __restrict__ T3)
{
    const int bid = blockIdx.x;
    if (bid < 8192) {
        long i = ((long)bid * 256 + threadIdx.x) * 4;
        f32x4 v = *(const f32x4*)(x + i);
        u16x4 o;
        #pragma unroll
        for (int r = 0; r < 4; ++r) o[r] = f2b(v[r]);
        *(u16x4*)(xb + i) = o;
        return;
    }
    const int b2 = bid - 8192;
    const float* W; unsigned short* T;
    switch (b2 >> 10) {
        case 0:  W = W0; T = T0; break;
        case 1:  W = W1; T = T1; break;
        case 2:  W = W2; T = T2; break;
        default: W = W3; T = T3; break;
    }
    const int tile = b2 & 1023;
    const int bx = (tile & 31) * 32, by = (tile >> 5) * 32;
    __shared__ float buf[32][33];
    const int tx = threadIdx.x & 31, ty = threadIdx.x >> 5;
    #pragma unroll
    for (int i = 0; i < 32; i += 8)
        buf[ty + i][tx] = W[(long)(by + ty + i) * D_MODEL + bx + tx];
    __syncthreads();
    #pragma unroll
    for (int i = 0; i < 32; i += 8)
        T[(long)(bx + ty + i) * D_MODEL + by + tx] = f2b(buf[tx][ty + i]);
}

extern "C" void kernel_launch(void* const* d_in, const int* in_sizes, int n_in,
                              void* d_out, int out_size, void* d_ws, size_t ws_size,
                              hipStream_t stream)
{
    const float* x  = (const float*)d_in[0];
    const float* Wq = (const float*)d_in[1];
    const float* bq = (const float*)d_in[2];
    const float* Wk = (const float*)d_in[3];
    const float* bk = (const float*)d_in[4];
    const float* Wv = (const float*)d_in[5];
    const float* bv = (const float*)d_in[6];
    const float* Wo = (const float*)d_in[7];
    const float* bo = (const float*)d_in[8];
    float* out = (float*)d_out;

    char* ws = (char*)d_ws;
    const size_t MB = 1024ull * 1024ull;
    unsigned short* Wqt = (unsigned short*)(ws + 0 * MB);
    unsigned short* Wkt = (unsigned short*)(ws + 2 * MB);
    unsigned short* Wvt = (unsigned short*)(ws + 4 * MB);
    unsigned short* Wot = (unsigned short*)(ws + 6 * MB);
    unsigned short* xb  = (unsigned short*)(ws + 8 * MB);    // 16MB
    unsigned short* Q   = (unsigned short*)(ws + 24 * MB);   // 16MB
    unsigned short* Kb  = (unsigned short*)(ws + 40 * MB);   // 16MB
    unsigned short* Vt  = (unsigned short*)(ws + 56 * MB);   // 16MB
    unsigned short* At  = (unsigned short*)(ws + 72 * MB);   // 16MB
    unsigned short* S   = (unsigned short*)(ws + 88 * MB);   // 32MB -> 120MB

    const dim3 blk(256);

    prep<<<dim3(12288), blk, 0, stream>>>(x, xb, Wq, Wk, Wv, Wo, Wqt, Wkt, Wvt, Wot);

    qkv_gemm<<<dim3(8, 64, 3), blk, 0, stream>>>(xb, Wqt, Wkt, Wvt, bq, bk, bv, Q, Kb, Vt);

    // scores[b] = Q[b] @ K[b]^T (raw; scale folded into softmax)
    gemm_bt<false, unsigned short><<<dim3(16, 16, 4), blk, 0, stream>>>(
        Q, Kb, nullptr, S, 2048, 1024,
        (long)2048 * 1024, (long)2048 * 1024, (long)2048 * 2048);

    softmax_inplace<<<dim3(NBATCH * SEQ), blk, 0, stream>>>(S);

    // attn[b] = P[b] @ V[b]
    gemm_bt<false, unsigned short><<<dim3(8, 16, 4), blk, 0, stream>>>(
        S, Vt, nullptr, At, 1024, 2048,
        (long)2048 * 2048, (long)1024 * 2048, (long)2048 * 1024);

    // out = attn @ Wo + bo (fp32 store)
    gemm_bt<true, float><<<dim3(8, 64, 1), blk, 0, stream>>>(
        At, Wot, bo, out, 1024, 1024, 0, 0, 0);
}

// Round 4
// 276.437 us; speedup vs baseline: 1.1363x; 1.1363x over previous
//
#include <hip/hip_runtime.h>
#include <stdint.h>

#define D_MODEL 1024
#define SEQ 2048
#define NBATCH 4

typedef __attribute__((ext_vector_type(4))) float f32x4;
typedef __attribute__((ext_vector_type(8))) __bf16 bf16x8;
typedef __attribute__((ext_vector_type(4))) unsigned short u16x4;

__device__ __forceinline__ float b2f(unsigned short u) {
    union { unsigned int i; float f; } c; c.i = ((unsigned int)u) << 16; return c.f;
}
__device__ __forceinline__ unsigned short f2b(float f) {
    union { float f; unsigned int i; } c; c.f = f;
    unsigned int u = c.i;
    u += 0x7FFFu + ((u >> 16) & 1u);
    return (unsigned short)(u >> 16);
}

__device__ __forceinline__ void glds16(void* lds, const void* g) {
    __builtin_amdgcn_global_load_lds((const __attribute__((address_space(1))) void*)g,
                                     (__attribute__((address_space(3))) void*)lds,
                                     16, 0, 0);
}

// XCD-aware tile remap (8 XCDs, bid%8 = xcd). Each XCD owns a contiguous
// y-band of height gy/8 across all x,z so its L2 holds only its A-band + the
// shared B panel. Pure permutation; requires gy % 8 == 0 (grids: gy in {16,64}).
__device__ __forceinline__ void xcd_map(int& xx, int& yy, int& zz)
{
    const int gx = gridDim.x, gy = gridDim.y;
    int bid = blockIdx.x + gx * (blockIdx.y + gy * blockIdx.z);
    const int H = gy >> 3;
    const int xcd = bid & 7;
    int slot = bid >> 3;
    yy = xcd * H + (slot % H);
    slot /= H;
    xx = slot % gx;
    zz = slot / gx;
}

// ---------------------------------------------------------------------------
// GEMM core: BK=64, DOUBLE-BUFFERED, stage-before-compute, drain-per-step.
// Per iteration:
//   STAGE(tile k+1 -> buf^1)    // 8 x global_load_lds issued first
//   ds_read(buf) + 32 MFMA      // ~350 cyc of compute overlapping the loads
//   __syncthreads()             // vmcnt(0)+lgkmcnt(0)+s_barrier (compiler)
// vs round-0 (issue -> drain immediately -> compute): the full load latency
// was exposed every K-step; here compute covers most of it. vs round-2
// (BK=32): half the number of drains, 2x the compute per drain.
// Correctness by construction (passed twice with this discipline):
//  - reads of buf are register-consumed (compiler lgkmcnt) before the sync;
//    next iteration's writes to buf are issued after the sync -> no WAR.
//  - writes to buf^1 are fully landed at the sync (vmcnt(0)) before any
//    read of buf^1 next iteration -> no RAW.
// LDS layout per buffer (byte-identical to round-0's verified mapping):
// [128 rows][64 cols] bf16, 128B rows, 8x16B slots/row. XOR swizzle: slot
// (row,sc) holds chunk sc^(row&7), permuted on the glds *source* side
// (LDS writes are linear: base + lane*16); readers fetch slot (q^(fr&7))
// -> 2-way banking (free; measured 0 conflicts).
// ---------------------------------------------------------------------------
__device__ __forceinline__ void gemm_tile(const unsigned short* __restrict__ A,
                                          const unsigned short* __restrict__ Bt,
                                          int K, int m0, int n0,
                                          f32x4 (&acc)[4][4])
{
    __shared__ alignas(16) unsigned short As[2 * 128 * 64];   // 32KB
    __shared__ alignas(16) unsigned short Bs[2 * 128 * 64];   // 32KB

    const int t    = threadIdx.x;
    const int wave = t >> 6;
    const int srow = t >> 3;                        // row within j-group (0..31)
    const int sch  = ((t & 7) ^ (srow & 7)) * 8;    // permuted source chunk (elems)

    const unsigned short* Ag = A  + (long)(m0 + srow) * K + sch;
    const unsigned short* Bg = Bt + (long)(n0 + srow) * K + sch;

    char* AsB = (char*)As + wave * 1024;            // wave-uniform glds base
    char* BsB = (char*)Bs + wave * 1024;

    const int wm   = (wave >> 1) * 64;
    const int wn   = (wave & 1) * 64;
    const int lane = t & 63;
    const int frr  = lane & 15;
    const int quad = lane >> 4;
    const int rp0  = ((quad    ) ^ (frr & 7)) * 16;
    const int rp1  = ((4 + quad) ^ (frr & 7)) * 16;

    auto stage = [&](int buf, int ko) {
        #pragma unroll
        for (int j = 0; j < 4; ++j) {
            glds16(AsB + buf * 16384 + j * 4096, Ag + (long)(j * 32) * K + ko);
            glds16(BsB + buf * 16384 + j * 4096, Bg + (long)(j * 32) * K + ko);
        }
    };

    stage(0, 0);
    __syncthreads();

    int buf = 0;
    for (int k0 = 0; k0 < K; k0 += 64) {
        if (k0 + 64 < K) stage(buf ^ 1, k0 + 64);   // issue next tile first

        #pragma unroll
        for (int s = 0; s < 2; ++s) {
            const int ro = s ? rp1 : rp0;
            bf16x8 af[4], bfv[4];
            #pragma unroll
            for (int i = 0; i < 4; ++i)
                af[i] = *(const bf16x8*)((const char*)As + buf * 16384
                                         + (wm + i * 16 + frr) * 128 + ro);
            #pragma unroll
            for (int i = 0; i < 4; ++i)
                bfv[i] = *(const bf16x8*)((const char*)Bs + buf * 16384
                                          + (wn + i * 16 + frr) * 128 + ro);

            #pragma unroll
            for (int mi = 0; mi < 4; ++mi)
                #pragma unroll
                for (int ni = 0; ni < 4; ++ni)
                    acc[mi][ni] = __builtin_amdgcn_mfma_f32_16x16x32_bf16(
                                      af[mi], bfv[ni], acc[mi][ni], 0, 0, 0);
        }

        __syncthreads();                            // drain + barrier
        buf ^= 1;
    }
}

// Plain-store GEMM, z-batched via element strides. OutT = ushort(bf16) | float.
template<bool BIAS, typename OutT>
__global__ __launch_bounds__(256)
void gemm_bt(const unsigned short* __restrict__ A,
             const unsigned short* __restrict__ Bt,
             const float* __restrict__ bias,
             OutT* __restrict__ C,
             int N, int K, long sA, long sB, long sC)
{
    int xx, yy, zz;
    xcd_map(xx, yy, zz);
    A  += (long)zz * sA;
    Bt += (long)zz * sB;
    C  += (long)zz * sC;
    const int m0 = yy * 128;
    const int n0 = xx * 128;

    f32x4 acc[4][4] = {};
    gemm_tile(A, Bt, K, m0, n0, acc);

    const int t = threadIdx.x, wave = t >> 6, lane = t & 63;
    const int wm = (wave >> 1) * 64, wn = (wave & 1) * 64;
    const int fr = lane & 15, quad = lane >> 4;

    float bb[4] = {0.f, 0.f, 0.f, 0.f};
    if (BIAS) {
        #pragma unroll
        for (int ni = 0; ni < 4; ++ni)
            bb[ni] = bias[n0 + wn + ni * 16 + fr];
    }

    // C/D layout (HW-verified): col = lane&15, row = quad*4 + reg
    #pragma unroll
    for (int mi = 0; mi < 4; ++mi) {
        const int rowb = m0 + wm + mi * 16 + quad * 4;
        #pragma unroll
        for (int ni = 0; ni < 4; ++ni) {
            const int col = n0 + wn + ni * 16 + fr;
            f32x4 v = acc[mi][ni];
            if constexpr (sizeof(OutT) == 4) {
                #pragma unroll
                for (int r = 0; r < 4; ++r)
                    C[(long)(rowb + r) * N + col] = v[r] + bb[ni];
            } else {
                #pragma unroll
                for (int r = 0; r < 4; ++r)
                    C[(long)(rowb + r) * N + col] = (OutT)f2b(v[r] + bb[ni]);
            }
        }
    }
}

// Fused QKV projection: grid (8, 64, 3); remapped z selects weight/bias/output.
// V (z==2) stores transposed per batch: Vt[b][n][s], b = row>>11, s = row&2047.
__global__ __launch_bounds__(256)
void qkv_gemm(const unsigned short* __restrict__ xb,
              const unsigned short* __restrict__ Wqt,
              const unsigned short* __restrict__ Wkt,
              const unsigned short* __restrict__ Wvt,
              const float* __restrict__ bq, const float* __restrict__ bk,
              const float* __restrict__ bv,
              unsigned short* __restrict__ Q, unsigned short* __restrict__ Kb,
              unsigned short* __restrict__ Vt)
{
    int xx, yy, zz;
    xcd_map(xx, yy, zz);

    const unsigned short* Bt; const float* bias; unsigned short* C; bool tstore = false;
    switch (zz) {
        case 0:  Bt = Wqt; bias = bq; C = Q;  break;
        case 1:  Bt = Wkt; bias = bk; C = Kb; break;
        default: Bt = Wvt; bias = bv; C = Vt; tstore = true; break;
    }
    const int m0 = yy * 128;
    const int n0 = xx * 128;
    const int N = D_MODEL, K = D_MODEL;

    f32x4 acc[4][4] = {};
    gemm_tile(xb, Bt, K, m0, n0, acc);

    const int t = threadIdx.x, wave = t >> 6, lane = t & 63;
    const int wm = (wave >> 1) * 64, wn = (wave & 1) * 64;
    const int fr = lane & 15, quad = lane >> 4;

    float bb[4];
    #pragma unroll
    for (int ni = 0; ni < 4; ++ni)
        bb[ni] = bias[n0 + wn + ni * 16 + fr];

    #pragma unroll
    for (int mi = 0; mi < 4; ++mi) {
        const int rowb = m0 + wm + mi * 16 + quad * 4;
        #pragma unroll
        for (int ni = 0; ni < 4; ++ni) {
            const int col = n0 + wn + ni * 16 + fr;
            f32x4 v = acc[mi][ni];
            if (!tstore) {
                #pragma unroll
                for (int r = 0; r < 4; ++r)
                    C[(long)(rowb + r) * N + col] = f2b(v[r] + bb[ni]);
            } else {
                u16x4 pk;
                #pragma unroll
                for (int r = 0; r < 4; ++r)
                    pk[r] = f2b(v[r] + bb[ni]);
                unsigned short* dst = C + ((long)(rowb >> 11)) * ((long)N * SEQ)
                                        + (long)col * SEQ + (rowb & (SEQ - 1));
                *(u16x4*)dst = pk;
            }
        }
    }
}

// In-place softmax over rows of 2048 bf16 raw scores, 1/sqrt(1024) folded in.
__global__ __launch_bounds__(256)
void softmax_inplace(unsigned short* __restrict__ S)
{
    const long row = blockIdx.x;
    unsigned short* s = S + row * SEQ;
    const int t = threadIdx.x;

    u16x4 a = ((const u16x4*)s)[t];
    u16x4 b = ((const u16x4*)s)[t + 256];
    float v[8];
    #pragma unroll
    for (int i = 0; i < 4; ++i) { v[i] = b2f(a[i]); v[4 + i] = b2f(b[i]); }

    float mx = v[0];
    #pragma unroll
    for (int i = 1; i < 8; ++i) mx = fmaxf(mx, v[i]);
    #pragma unroll
    for (int off = 32; off; off >>= 1) mx = fmaxf(mx, __shfl_xor(mx, off));

    __shared__ float red[8];
    const int wv = t >> 6, ln = t & 63;
    if (ln == 0) red[wv] = mx;
    __syncthreads();
    mx = fmaxf(fmaxf(red[0], red[1]), fmaxf(red[2], red[3]));

    const float sc = 0.03125f;
    float e[8], sum = 0.f;
    #pragma unroll
    for (int i = 0; i < 8; ++i) { e[i] = __expf((v[i] - mx) * sc); sum += e[i]; }
    #pragma unroll
    for (int off = 32; off; off >>= 1) sum += __shfl_xor(sum, off);
    if (ln == 0) red[4 + wv] = sum;
    __syncthreads();
    sum = (red[4] + red[5]) + (red[6] + red[7]);
    const float inv = 1.f / sum;

    u16x4 o;
    #pragma unroll
    for (int i = 0; i < 4; ++i) o[i] = f2b(e[i] * inv);
    ((u16x4*)s)[t] = o;
    #pragma unroll
    for (int i = 0; i < 4; ++i) o[i] = f2b(e[4 + i] * inv);
    ((u16x4*)s)[t + 256] = o;
}

// Fused prep: blocks [0,8192) cast x fp32->bf16 (1024 elems each);
// blocks [8192,12288) transpose+cast the four weights (32x32 tiles).
__global__ __launch_bounds__(256)
void prep(const float* __restrict__ x, unsigned short* __restrict__ xb,
          const float* __restrict__ W0, const float* __restrict__ W1,
          const float* __restrict__ W2, const float* __restrict__ W3,
          unsigned short* __restrict__ T0, unsigned short* __restrict__ T1,
          unsigned short* __restrict__ T2, unsigned short* __restrict__ T3)
{
    const int bid = blockIdx.x;
    if (bid < 8192) {
        long i = ((long)bid * 256 + threadIdx.x) * 4;
        f32x4 v = *(const f32x4*)(x + i);
        u16x4 o;
        #pragma unroll
        for (int r = 0; r < 4; ++r) o[r] = f2b(v[r]);
        *(u16x4*)(xb + i) = o;
        return;
    }
    const int b2 = bid - 8192;
    const float* W; unsigned short* T;
    switch (b2 >> 10) {
        case 0:  W = W0; T = T0; break;
        case 1:  W = W1; T = T1; break;
        case 2:  W = W2; T = T2; break;
        default: W = W3; T = T3; break;
    }
    const int tile = b2 & 1023;
    const int bx = (tile & 31) * 32, by = (tile >> 5) * 32;
    __shared__ float buf[32][33];
    const int tx = threadIdx.x & 31, ty = threadIdx.x >> 5;
    #pragma unroll
    for (int i = 0; i < 32; i += 8)
        buf[ty + i][tx] = W[(long)(by + ty + i) * D_MODEL + bx + tx];
    __syncthreads();
    #pragma unroll
    for (int i = 0; i < 32; i += 8)
        T[(long)(bx + ty + i) * D_MODEL + by + tx] = f2b(buf[tx][ty + i]);
}

extern "C" void kernel_launch(void* const* d_in, const int* in_sizes, int n_in,
                              void* d_out, int out_size, void* d_ws, size_t ws_size,
                              hipStream_t stream)
{
    const float* x  = (const float*)d_in[0];
    const float* Wq = (const float*)d_in[1];
    const float* bq = (const float*)d_in[2];
    const float* Wk = (const float*)d_in[3];
    const float* bk = (const float*)d_in[4];
    const float* Wv = (const float*)d_in[5];
    const float* bv = (const float*)d_in[6];
    const float* Wo = (const float*)d_in[7];
    const float* bo = (const float*)d_in[8];
    float* out = (float*)d_out;

    char* ws = (char*)d_ws;
    const size_t MB = 1024ull * 1024ull;
    unsigned short* Wqt = (unsigned short*)(ws + 0 * MB);
    unsigned short* Wkt = (unsigned short*)(ws + 2 * MB);
    unsigned short* Wvt = (unsigned short*)(ws + 4 * MB);
    unsigned short* Wot = (unsigned short*)(ws + 6 * MB);
    unsigned short* xb  = (unsigned short*)(ws + 8 * MB);    // 16MB
    unsigned short* Q   = (unsigned short*)(ws + 24 * MB);   // 16MB
    unsigned short* Kb  = (unsigned short*)(ws + 40 * MB);   // 16MB
    unsigned short* Vt  = (unsigned short*)(ws + 56 * MB);   // 16MB
    unsigned short* At  = (unsigned short*)(ws + 72 * MB);   // 16MB
    unsigned short* S   = (unsigned short*)(ws + 88 * MB);   // 32MB -> 120MB

    const dim3 blk(256);

    prep<<<dim3(12288), blk, 0, stream>>>(x, xb, Wq, Wk, Wv, Wo, Wqt, Wkt, Wvt, Wot);

    qkv_gemm<<<dim3(8, 64, 3), blk, 0, stream>>>(xb, Wqt, Wkt, Wvt, bq, bk, bv, Q, Kb, Vt);

    // scores[b] = Q[b] @ K[b]^T (raw; scale folded into softmax)
    gemm_bt<false, unsigned short><<<dim3(16, 16, 4), blk, 0, stream>>>(
        Q, Kb, nullptr, S, 2048, 1024,
        (long)2048 * 1024, (long)2048 * 1024, (long)2048 * 2048);

    softmax_inplace<<<dim3(NBATCH * SEQ), blk, 0, stream>>>(S);

    // attn[b] = P[b] @ V[b]
    gemm_bt<false, unsigned short><<<dim3(8, 16, 4), blk, 0, stream>>>(
        S, Vt, nullptr, At, 1024, 2048,
        (long)2048 * 2048, (long)1024 * 2048, (long)2048 * 1024);

    // out = attn @ Wo + bo (fp32 store)
    gemm_bt<true, float><<<dim3(8, 64, 1), blk, 0, stream>>>(
        At, Wot, bo, out, 1024, 1024, 0, 0, 0);
}